// Round 6
// baseline (379.404 us; speedup 1.0000x reference)
//
#include <hip/hip_runtime.h>

// ---------------------------------------------------------------------------
// MultiDiscreteACTLayer: B=131072 rows, D=256.
// Per row: 8 users x 16 sc logits + 8 heads x 10 pow logits = 208 dots of 256.
// JAX threefry, PARTITIONABLE semantics (jax>=0.4.36 default):
//   split(key,8)[u] = threefry2x32(key, (0, u))          (foldlike, both words)
//   fold_in(key, d) = threefry2x32(key, (0, d))          (both words)
//   random_bits 32-bit, element i: (b1,b2)=tf2(key,(0,i)); bits = b1 ^ b2
// Output (float32): actions (B,16) | logp_sum (B,1) | avail (B,16).
// R14 (from R13): TWO-KERNEL SPLIT. R13's pipes sum to ~160us but wall=231:
//   barrier-serialized phases at ~2 blocks/CU never overlap. Split:
//   - gemm_kernel: R13 Phase A verbatim, stores logits to HBM workspace
//     TRANSPOSED lgT[col][B] via global_store_dwordx4 (lane's C-fragment =
//     4 consecutive rows; a wave's q-groups complete full 64B lines).
//     LDS = xb only (50.7KB), 3 blocks/CU.
//   - sample_kernel: Phase B/C verbatim (fast gumbel + certainty fallback,
//     DPP trees), 256-thr blocks, 5KB LDS, ~48 VGPR -> up to 8 blocks/CU;
//     VALU latency hidden by TLP. lgT reads: one 64B line = 16 rows of one
//     col = one block's row range, read once (~109MB clean stream).
//   Cost +218MB HBM (~35us) vs removing ~90us serialization. Numerics and
//   decisions bit-identical to R13. If ws_size < ~104MiB, falls back to the
//   R13 single-kernel (kept below).
// ---------------------------------------------------------------------------

#define B_TOTAL 131072
#define NCOL    208      // 8 users * (16 sc + 10 pow)
#define ROWS    32       // rows per block (gemm / fallback)
#define TINYF   1.17549435e-38f
#define THRF    2.0e-3f  // certainty threshold on top-2 gap (bound ~4e-5)

// W limb plane geometry (shorts): per (tile,chunk) 512, per tile 8*512=4096,
// per plane 13*4096 = 53248. Three planes.
#define WPLANE  53248
#define XB_L    8448     // x limb stride in shorts: 32 rows * 264 pitch
#define XB_P    264      // x row pitch in shorts (16B-aligned, bank-spread)
#define LGP     36       // lgT row pitch in floats (fallback kernel only)

typedef float f32x4 __attribute__((ext_vector_type(4)));
typedef short short8 __attribute__((ext_vector_type(8)));

#define MFMA_BF16(A,B,C) __builtin_amdgcn_mfma_f32_16x16x32_bf16((A),(B),(C),0,0,0)

// DPP row_ror within 16-lane rows (gfx9+ DPP row = 16 lanes).
#define ROR16(v, n) __uint_as_float((unsigned)__builtin_amdgcn_update_dpp(     \
    (int)__float_as_uint(v), (int)__float_as_uint(v), 0x120 | (n), 0xF, 0xF, false))

__device__ __forceinline__ float redmax16(float v) {
  v = fmaxf(v, ROR16(v, 8));
  v = fmaxf(v, ROR16(v, 4));
  v = fmaxf(v, ROR16(v, 2));
  v = fmaxf(v, ROR16(v, 1));
  return v;
}
__device__ __forceinline__ float redsum16(float v) {
  v += ROR16(v, 8);
  v += ROR16(v, 4);
  v += ROR16(v, 2);
  v += ROR16(v, 1);
  return v;
}

struct TF2 { unsigned a, b; };

__host__ __device__ constexpr unsigned rotl_(unsigned x, int r) {
  return (x << r) | (x >> (32 - r));
}

// Threefry-2x32, 20 rounds, exactly as JAX/Random123.
__host__ __device__ constexpr TF2 tf2(unsigned k0, unsigned k1, unsigned x0, unsigned x1) {
  unsigned ks0 = k0, ks1 = k1, ks2 = k0 ^ k1 ^ 0x1BD11BDAu;
  x0 += ks0; x1 += ks1;
  x0 += x1; x1 = rotl_(x1, 13); x1 ^= x0;
  x0 += x1; x1 = rotl_(x1, 15); x1 ^= x0;
  x0 += x1; x1 = rotl_(x1, 26); x1 ^= x0;
  x0 += x1; x1 = rotl_(x1,  6); x1 ^= x0;
  x0 += ks1; x1 += ks2 + 1u;
  x0 += x1; x1 = rotl_(x1, 17); x1 ^= x0;
  x0 += x1; x1 = rotl_(x1, 29); x1 ^= x0;
  x0 += x1; x1 = rotl_(x1, 16); x1 ^= x0;
  x0 += x1; x1 = rotl_(x1, 24); x1 ^= x0;
  x0 += ks2; x1 += ks0 + 2u;
  x0 += x1; x1 = rotl_(x1, 13); x1 ^= x0;
  x0 += x1; x1 = rotl_(x1, 15); x1 ^= x0;
  x0 += x1; x1 = rotl_(x1, 26); x1 ^= x0;
  x0 += x1; x1 = rotl_(x1,  6); x1 ^= x0;
  x0 += ks0; x1 += ks1 + 3u;
  x0 += x1; x1 = rotl_(x1, 17); x1 ^= x0;
  x0 += x1; x1 = rotl_(x1, 29); x1 ^= x0;
  x0 += x1; x1 = rotl_(x1, 16); x1 ^= x0;
  x0 += x1; x1 = rotl_(x1, 24); x1 ^= x0;
  x0 += ks1; x1 += ks2 + 4u;
  x0 += x1; x1 = rotl_(x1, 13); x1 ^= x0;
  x0 += x1; x1 = rotl_(x1, 15); x1 ^= x0;
  x0 += x1; x1 = rotl_(x1, 26); x1 ^= x0;
  x0 += x1; x1 = rotl_(x1,  6); x1 ^= x0;
  x0 += ks2; x1 += ks0 + 5u;
  return TF2{x0, x1};
}

// foldlike derivation from root key (0, 42) — all compile-time constants.
__host__ __device__ constexpr unsigned key_a(unsigned d) { return tf2(0u, 42u, 0u, d).a; }
__host__ __device__ constexpr unsigned key_b(unsigned d) { return tf2(0u, 42u, 0u, d).b; }

constexpr unsigned SK0c[8] = {
  key_a(0), key_a(1), key_a(2), key_a(3), key_a(4), key_a(5), key_a(6), key_a(7)
};
constexpr unsigned SK1c[8] = {
  key_b(0), key_b(1), key_b(2), key_b(3), key_b(4), key_b(5), key_b(6), key_b(7)
};
constexpr unsigned PK0 = key_a(999);
constexpr unsigned PK1 = key_b(999);

// Fast fp64 natural log, positive normal inputs (exact path; see R9 notes).
__device__ __forceinline__ double dlog(double xd) {
  long long b = __double_as_longlong(xd);
  int e = (int)(b >> 52) - 1023;
  double m = __longlong_as_double((b & 0x000FFFFFFFFFFFFFLL) | 0x3FF0000000000000LL);
  if (m > 1.4142135623730951) { m *= 0.5; e += 1; }
  double mp1 = m + 1.0;
  double r = (double)__builtin_amdgcn_rcpf((float)mp1);
  r = fma(fma(-mp1, r, 1.0), r, r);          // 1 Newton: ~1.4e-14 rel
  double z  = (m - 1.0) * r;
  double z2 = z * z;
  double p = fma(z2, fma(z2, fma(z2, fma(z2, fma(z2,
              1.0/13.0, 1.0/11.0), 1.0/9.0), 1.0/7.0), 1.0/5.0), 1.0/3.0);
  double lm = fma(2.0 * z, z2 * p, 2.0 * z);
  return fma((double)e, 0.6931471805599453, lm);
}

// JAX gumbel from raw bits, fp32 bit-ops replicated; logs in fp64 (dlog).
__device__ __forceinline__ float gumbelf(unsigned bits) {
  float u = __uint_as_float((bits >> 9) | 0x3f800000u) - 1.0f;   // [0,1)
  u = u + TINYF;
  u = fmaxf(TINYF, u);
  double nl = -dlog((double)u);            // in (5.9e-8, 87.4] — normal
  return -(float)dlog(nl);
}

// COLD path: exact gumbel, called only for uncertain argmax groups.
__device__ __attribute__((noinline)) float gumbel_precise(unsigned k0, unsigned k1,
                                                          unsigned cnt) {
  TF2 r = tf2(k0, k1, 0u, cnt);
  return gumbelf(r.a ^ r.b);
}

// HOT path: hw v_log_f32 gumbel; abs err <= ~4e-5 (R13 analysis). log1p
// polynomial for u near 1 where hw-log abs error is relatively large.
__device__ __forceinline__ float gumbel_fast(unsigned bits) {
  float u = __uint_as_float((bits >> 9) | 0x3f800000u) - 1.0f;   // [0,1)
  u = fmaxf(TINYF, u + TINYF);
  float t = u - 1.0f;                         // exact for u in [0.5, 1)
  float q  = fmaf(t, 0.33333333f, -0.5f);     // t/3 - 1/2
  float pl = -t * fmaf(t, q, 1.0f);           // -(t - t^2/2 + t^3/3)
  float hw = -__logf(u);
  float nl = (t > -0.0078125f) ? pl : hw;
  return -__logf(nl);
}

// ---------------------------------------------------------------------------
// Kernel 0: split W into 3 bf16 limb planes, fragment-ordered (see R9).
// ---------------------------------------------------------------------------
__global__ void repack_kernel(const float* __restrict__ Wsc, const float* __restrict__ bsc,
                              const float* __restrict__ Wpow, const float* __restrict__ bpow,
                              short* __restrict__ Wb, float* __restrict__ bp) {
  int t = blockIdx.x * 256 + threadIdx.x;   // [0, 53504)
  if (t < 53248) {
    int j    = t & 7;
    int lane = (t >> 3) & 63;
    int c    = (t >> 9) & 7;
    int T    = t >> 12;                     // 0..12
    int k    = c * 32 + (lane >> 4) * 8 + j;
    int col  = T * 16 + (lane & 15);        // < 208
    int u = col / 26, n = col % 26;
    float w = (n < 16) ? Wsc[(u * 256 + k) * 16 + n]
                       : Wpow[(u * 256 + k) * 10 + (n - 16)];
    unsigned b0 = __float_as_uint(w) & 0xFFFF0000u;
    float f1 = w - __uint_as_float(b0);
    unsigned b1 = __float_as_uint(f1) & 0xFFFF0000u;
    float f2 = f1 - __uint_as_float(b1);
    unsigned b2 = __float_as_uint(f2) & 0xFFFF0000u;
    int idx = (T * 8 + c) * 512 + lane * 8 + j;
    Wb[idx]              = (short)(b0 >> 16);
    Wb[WPLANE + idx]     = (short)(b1 >> 16);
    Wb[2 * WPLANE + idx] = (short)(b2 >> 16);
  } else {
    int cc = t - 53248;                     // [0,256)
    float v = 0.f;
    if (cc < NCOL) {
      int u = cc / 26, n = cc % 26;
      v = (n < 16) ? bsc[u * 16 + n] : bpow[u * 10 + (n - 16)];
    }
    bp[cc] = v;
  }
}

// 8 limb products (drop x2*W2 ~2^-32): accM = x0W0, accS = 7 small terms.
#define PROD8(X0, X1, X2, W0, W1, W2, AM, AS) do {                      \
    AM = MFMA_BF16(X0, W0, AM);                                         \
    AS = MFMA_BF16(X1, W0, AS);                                         \
    AS = MFMA_BF16(X0, W1, AS);                                         \
    AS = MFMA_BF16(X1, W1, AS);                                         \
    AS = MFMA_BF16(X2, W0, AS);                                         \
    AS = MFMA_BF16(X0, W2, AS);                                         \
    AS = MFMA_BF16(X2, W1, AS);                                         \
    AS = MFMA_BF16(X1, W2, AS);                                         \
  } while (0)

// Shared staging+GEMM body (Phase A of R13). Writes combined accs + labels.
#define PHASE_A_BODY(XB, DA0, DA1, DB0, DB1, I0, JO)                          \
  const int lane64 = t & 63;                                                  \
  const int wv  = t >> 6;                                                     \
  const int q   = lane64 >> 4;                                                \
  const int r16 = lane64 & 15;                                                \
  const int tA  = (wv + (blockIdx.x & 7)) & 7;                                \
  const bool heavy = tA < 5;                                                  \
  const int tB  = 8 + tA;                                                     \
  const f32x4 fz = {0.f, 0.f, 0.f, 0.f};                                      \
  {                                                                           \
    f32x4 mA0 = fz, sA0 = fz, mA1 = fz, sA1 = fz;                             \
    f32x4 mB0 = fz, sB0 = fz, mB1 = fz, sB1 = fz;                             \
    const short* xr0 = &XB[0][r16][0];                                        \
    const short* xr1 = &XB[0][16 + r16][0];                                   \
    const int wlane = lane64 * 8;                                             \
    _Pragma("unroll 1")                                                       \
    for (int c = 0; c < 8; ++c) {                                             \
      const int xo = c * 32 + q * 8;                                          \
      short8 a0 = *(const short8*)(xr0 + xo);                                 \
      short8 a1 = *(const short8*)(xr0 + XB_L + xo);                          \
      short8 a2 = *(const short8*)(xr0 + 2 * XB_L + xo);                      \
      short8 c0_ = *(const short8*)(xr1 + xo);                                \
      short8 c1_ = *(const short8*)(xr1 + XB_L + xo);                         \
      short8 c2_ = *(const short8*)(xr1 + 2 * XB_L + xo);                     \
      {                                                                       \
        const int wi = (tA * 8 + c) * 512 + wlane;                            \
        short8 w0 = *(const short8*)(Wb + wi);                                \
        short8 w1 = *(const short8*)(Wb + WPLANE + wi);                       \
        short8 w2 = *(const short8*)(Wb + 2 * WPLANE + wi);                   \
        PROD8(a0,  a1,  a2,  w0, w1, w2, mA0, sA0);                           \
        PROD8(c0_, c1_, c2_, w0, w1, w2, mA1, sA1);                           \
      }                                                                       \
      if (heavy) {                                                            \
        const int wi = (tB * 8 + c) * 512 + wlane;                            \
        short8 w0 = *(const short8*)(Wb + wi);                                \
        short8 w1 = *(const short8*)(Wb + WPLANE + wi);                       \
        short8 w2 = *(const short8*)(Wb + 2 * WPLANE + wi);                   \
        PROD8(a0,  a1,  a2,  w0, w1, w2, mB0, sB0);                           \
        PROD8(c0_, c1_, c2_, w0, w1, w2, mB1, sB1);                           \
      }                                                                       \
    }                                                                         \
    short8 pa = {0, 0, 0, 0, 0, 0, 0, 0};                                     \
    short8 pb = {0, 0, 0, 0, 0, 0, 0, 0};                                     \
    if (q == 0) {                                                             \
      pa[0] = (short)(__float_as_uint((float)r16) >> 16);                     \
      pb[0] = (short)0x3F80;                                                  \
    }                                                                         \
    f32x4 pr = MFMA_BF16(pa, pb, fz);                                         \
    f32x4 pc = MFMA_BF16(pb, pa, fz);                                         \
    I0 = ((int)(pr[0] + 0.5f)) & 15;                                          \
    JO = ((int)(pc[0] + 0.5f)) & 15;                                          \
    DA0 = mA0 + sA0; DA1 = mA1 + sA1;                                         \
    DB0 = mB0 + sB0; DB1 = mB1 + sB1;                                         \
  }

// x tile load + 3-limb split into LDS (shared by gemm and fallback kernels).
#define STAGE_X(XB)                                                           \
  _Pragma("unroll")                                                           \
  for (int i = 0; i < 4; ++i) {                                               \
    int flat = t + 512 * i;                                                   \
    int r  = flat >> 6;                                                       \
    int kq = flat & 63;                                                       \
    float4 v = ((const float4*)(x + (size_t)(b0 + r) * 256))[kq];             \
    unsigned L0[4], L1[4], L2[4];                                             \
    _Pragma("unroll")                                                         \
    for (int e = 0; e < 4; ++e) {                                             \
      float f = (&v.x)[e];                                                    \
      unsigned h0 = __float_as_uint(f) & 0xFFFF0000u;                         \
      float f1 = f - __uint_as_float(h0);                                     \
      unsigned h1 = __float_as_uint(f1) & 0xFFFF0000u;                        \
      float f2 = f1 - __uint_as_float(h1);                                    \
      unsigned h2 = __float_as_uint(f2) & 0xFFFF0000u;                        \
      L0[e] = h0; L1[e] = h1; L2[e] = h2;                                     \
    }                                                                         \
    int ks = 4 * kq;                                                          \
    *(uint2*)&XB[0][r][ks] =                                                  \
        make_uint2((L0[0] >> 16) | (L0[1] & 0xFFFF0000u),                     \
                   (L0[2] >> 16) | (L0[3] & 0xFFFF0000u));                    \
    *(uint2*)&XB[1][r][ks] =                                                  \
        make_uint2((L1[0] >> 16) | (L1[1] & 0xFFFF0000u),                     \
                   (L1[2] >> 16) | (L1[3] & 0xFFFF0000u));                    \
    *(uint2*)&XB[2][r][ks] =                                                  \
        make_uint2((L2[0] >> 16) | (L2[1] & 0xFFFF0000u),                     \
                   (L2[2] >> 16) | (L2[3] & 0xFFFF0000u));                    \
  }

// ---------------------------------------------------------------------------
// Kernel 1: GEMM only. 32 rows/block, 512 threads. Stores logits (+bias) to
// HBM workspace TRANSPOSED: lgT[col][B]. LDS = xb only (50688 B).
// ---------------------------------------------------------------------------
__global__ __launch_bounds__(512, 4) void gemm_kernel(
    const float* __restrict__ x, const short* __restrict__ Wb,
    const float* __restrict__ bp, float* __restrict__ lgT) {
  __shared__ __align__(16) short xb[3][ROWS][XB_P];
  const int t = threadIdx.x;
  const int b0 = blockIdx.x * ROWS;

  STAGE_X(xb)
  __syncthreads();

  f32x4 dA0, dA1, dB0, dB1;
  int i0, jo;
  PHASE_A_BODY(xb, dA0, dA1, dB0, dB1, i0, jo)

  // stores: lane holds col cA, rows b0+i0..+3 and b0+16+i0..+3 (contiguous).
  {
    const int cA = tA * 16 + jo;
    float bpA = bp[cA];
    float4 v0, v1;
    v0.x = dA0[0] + bpA; v0.y = dA0[1] + bpA; v0.z = dA0[2] + bpA; v0.w = dA0[3] + bpA;
    v1.x = dA1[0] + bpA; v1.y = dA1[1] + bpA; v1.z = dA1[2] + bpA; v1.w = dA1[3] + bpA;
    float* base = lgT + (size_t)cA * B_TOTAL + b0;
    *(float4*)(base + i0)      = v0;
    *(float4*)(base + 16 + i0) = v1;
    if (heavy) {
      const int cB = tB * 16 + jo;
      float bpB = bp[cB];
      v0.x = dB0[0] + bpB; v0.y = dB0[1] + bpB; v0.z = dB0[2] + bpB; v0.w = dB0[3] + bpB;
      v1.x = dB1[0] + bpB; v1.y = dB1[1] + bpB; v1.z = dB1[2] + bpB; v1.w = dB1[3] + bpB;
      float* baseB = lgT + (size_t)cB * B_TOTAL + b0;
      *(float4*)(baseB + i0)      = v0;
      *(float4*)(baseB + 16 + i0) = v1;
    }
  }
}

// ---------------------------------------------------------------------------
// Kernel 2: sampler. 16 rows/block, 256 threads, 16 lanes per row.
// Reads lgT[col][B] (coalesced: one 64B line = this block's 16 rows of one
// col). Fast gumbel + certainty fallback + DPP trees, as R13 Phase B/C.
// ---------------------------------------------------------------------------
__global__ __launch_bounds__(256, 4) void sample_kernel(
    const float* __restrict__ lgT, const int* __restrict__ avail,
    float* __restrict__ out) {
  __shared__ float gpow[16][80];
  const int t = threadIdx.x;
  const int b0 = blockIdx.x * 16;
  const int row  = t >> 4;
  const int lane = t & 15;
  const int gb   = b0 + row;
  const int av = avail[(size_t)gb * 16 + lane];

  // sc logits: 8 scalar loads, hoisted early (independent of gumbels).
  float lsc[8];
#pragma unroll
  for (int u = 0; u < 8; ++u)
    lsc[u] = lgT[(size_t)(u * 26 + lane) * B_TOTAL + gb];

  // pow gumbels -> LDS: 16 rows x 80, 5 per thread; magic-mul div.
#pragma unroll
  for (int i = 0; i < 5; ++i) {
    int flat = t + 256 * i;                       // [0, 1280)
    int prw  = (flat * 13108) >> 20;              // flat / 80
    int q80  = flat - prw * 80;
    unsigned cnt = (unsigned)((b0 + prw) * 80 + q80);
    TF2 r = tf2(PK0, PK1, 0u, cnt);
    gpow[prw][q80] = gumbel_fast(r.a ^ r.b);
  }

  // sc gumbels straight into registers (generator thread == consumer).
  float gsc[8];
  const unsigned cnt_sc = (unsigned)(gb * 16 + lane);
#pragma unroll
  for (int u = 0; u < 8; ++u) {
    TF2 r = tf2(SK0c[u], SK1c[u], 0u, cnt_sc);
    gsc[u] = gumbel_fast(r.a ^ r.b);
  }
  __syncthreads();

  const int g16  = (t & 63) >> 4;
  const int shamt = g16 * 16;
  const unsigned avm = (unsigned)((__ballot(av > 0) >> shamt) & 0xFFFFull);
  int stat = 0;
  float lpsum = 0.0f;
  float my_act = 0.0f;

  // sc scan: 8 users, sequential (sc_stat dependency)
#pragma unroll
  for (int u = 0; u < 8; ++u) {
    float logit = lsc[u];
    float ml = (stat < 2) ? logit : -1e10f;
    float y  = ml + gsc[u];
    float vmax = redmax16(y);
    unsigned bal = (unsigned)((__ballot(vmax - y < THRF) >> shamt) & 0xFFFFull);
    int idx;
    if (__builtin_popcount(bal) > 1) {          // uncertain: exact replay
      float gp = gumbel_precise(SK0c[u], SK1c[u], cnt_sc);
      float yp = ml + gp;
      float vp = redmax16(yp);
      idx = __builtin_ctz((unsigned)((__ballot(yp == vp) >> shamt) & 0xFFFFull));
    } else {
      idx = __builtin_ctz(bal);
    }
    float s = redsum16(__expf(ml));                 // softmax denom (no shift)
    float mlidx = redmax16((lane == idx) ? ml : -3.0e38f);  // broadcast ml[idx]
    float lp = mlidx - __logf(s);
    int au = (int)((avm >> u) & 1u);
    if (au) {
      lpsum += lp;
      if (lane == idx) stat += 1;
    }
    if (lane == u) my_act = au ? (float)idx : -1.0f;
  }

  // pow heads: independent
#pragma unroll
  for (int h = 0; h < 8; ++h) {
    bool on = lane < 10;
    float logit = on ? lgT[(size_t)(h * 26 + 16 + lane) * B_TOTAL + gb] : -3.0e38f;
    float y     = on ? (logit + gpow[row][h * 10 + lane]) : -3.0e38f;
    float vmax = redmax16(y);
    unsigned bal = (unsigned)((__ballot(vmax - y < THRF) >> shamt) & 0xFFFFull);
    int idx;
    if (__builtin_popcount(bal) > 1) {          // uncertain: exact replay
      float gp = gumbel_precise(PK0, PK1, (unsigned)(gb * 80 + h * 10 + lane));
      float yp = on ? (logit + gp) : -3.0e38f;
      float vp = redmax16(yp);
      idx = __builtin_ctz((unsigned)((__ballot(yp == vp) >> shamt) & 0xFFFFull));
    } else {
      idx = __builtin_ctz(bal);
    }
    float s = redsum16(on ? __expf(logit) : 0.0f);
    float mlidx = redmax16((lane == idx) ? logit : -3.0e38f);
    float lp = mlidx - __logf(s);
    int ah = (int)((avm >> (8 + h)) & 1u);
    if (ah) lpsum += lp;
    if (lane == 8 + h) my_act = ah ? (float)idx : -1.0f;
  }

  // ---- stores (all float32) ----
  out[(size_t)gb * 16 + lane] = my_act;                                // actions
  if (lane == 0) out[(size_t)B_TOTAL * 16 + gb] = lpsum;               // logp sum
  out[(size_t)B_TOTAL * 17 + (size_t)gb * 16 + lane] = (float)av;      // avail
}

// ---------------------------------------------------------------------------
// Fallback: R13 single-kernel (used only if ws_size can't hold lgT).
// ---------------------------------------------------------------------------
__global__ __launch_bounds__(512, 4) void act_kernel(
    const float* __restrict__ x, const int* __restrict__ avail,
    const short* __restrict__ Wb, const float* __restrict__ bp,
    float* __restrict__ out) {
  __shared__ __align__(16) union SMem {
    short xb[3][ROWS][XB_P];
    struct {
      float gpow[ROWS][80];
      float lgT[NCOL][LGP];
    } c;
  } sm;

  const int t = threadIdx.x;
  const int b0 = blockIdx.x * ROWS;
  const int av = avail[(size_t)(b0 + (t >> 4)) * 16 + (t & 15)];

  STAGE_X(sm.xb)
  __syncthreads();

  f32x4 dA0, dA1, dB0, dB1;
  int i0, jo;
  PHASE_A_BODY(sm.xb, dA0, dA1, dB0, dB1, i0, jo)
  __syncthreads();   // all xb reads done; slab now owned by gpow/lgT

  {
    const int cA = tA * 16 + jo;
    float bpA = bp[cA];
    float4 v0, v1;
    v0.x = dA0[0] + bpA; v0.y = dA0[1] + bpA; v0.z = dA0[2] + bpA; v0.w = dA0[3] + bpA;
    v1.x = dA1[0] + bpA; v1.y = dA1[1] + bpA; v1.z = dA1[2] + bpA; v1.w = dA1[3] + bpA;
    *(float4*)&sm.c.lgT[cA][i0]      = v0;
    *(float4*)&sm.c.lgT[cA][16 + i0] = v1;
    if (heavy) {
      const int cB = tB * 16 + jo;
      float bpB = bp[cB];
      v0.x = dB0[0] + bpB; v0.y = dB0[1] + bpB; v0.z = dB0[2] + bpB; v0.w = dB0[3] + bpB;
      v1.x = dB1[0] + bpB; v1.y = dB1[1] + bpB; v1.z = dB1[2] + bpB; v1.w = dB1[3] + bpB;
      *(float4*)&sm.c.lgT[cB][i0]      = v0;
      *(float4*)&sm.c.lgT[cB][16 + i0] = v1;
    }
  }

#pragma unroll
  for (int i = 0; i < 5; ++i) {
    int flat = t + 512 * i;
    int prw  = (flat * 13108) >> 20;
    int q80  = flat - prw * 80;
    unsigned cnt = (unsigned)((b0 + prw) * 80 + q80);
    TF2 r = tf2(PK0, PK1, 0u, cnt);
    sm.c.gpow[prw][q80] = gumbel_fast(r.a ^ r.b);
  }

  float gsc[8];
  const unsigned cnt_sc = (unsigned)((b0 + (t >> 4)) * 16 + (t & 15));
#pragma unroll
  for (int u = 0; u < 8; ++u) {
    TF2 r = tf2(SK0c[u], SK1c[u], 0u, cnt_sc);
    gsc[u] = gumbel_fast(r.a ^ r.b);
  }
  __syncthreads();

  const int row  = t >> 4;
  const int lane = t & 15;
  const int g16  = (t & 63) >> 4;
  const int shamt = g16 * 16;
  const int gb   = b0 + row;
  const unsigned avm = (unsigned)((__ballot(av > 0) >> shamt) & 0xFFFFull);
  int stat = 0;
  float lpsum = 0.0f;
  float my_act = 0.0f;

#pragma unroll
  for (int u = 0; u < 8; ++u) {
    float logit = sm.c.lgT[u * 26 + lane][row];
    float ml = (stat < 2) ? logit : -1e10f;
    float y  = ml + gsc[u];
    float vmax = redmax16(y);
    unsigned bal = (unsigned)((__ballot(vmax - y < THRF) >> shamt) & 0xFFFFull);
    int idx;
    if (__builtin_popcount(bal) > 1) {
      float gp = gumbel_precise(SK0c[u], SK1c[u], cnt_sc);
      float yp = ml + gp;
      float vp = redmax16(yp);
      idx = __builtin_ctz((unsigned)((__ballot(yp == vp) >> shamt) & 0xFFFFull));
    } else {
      idx = __builtin_ctz(bal);
    }
    float s = redsum16(__expf(ml));
    float mlidx = redmax16((lane == idx) ? ml : -3.0e38f);
    float lp = mlidx - __logf(s);
    int au = (int)((avm >> u) & 1u);
    if (au) {
      lpsum += lp;
      if (lane == idx) stat += 1;
    }
    if (lane == u) my_act = au ? (float)idx : -1.0f;
  }

#pragma unroll
  for (int h = 0; h < 8; ++h) {
    bool on = lane < 10;
    float logit = on ? sm.c.lgT[h * 26 + 16 + lane][row] : -3.0e38f;
    float y     = on ? (logit + sm.c.gpow[row][h * 10 + lane]) : -3.0e38f;
    float vmax = redmax16(y);
    unsigned bal = (unsigned)((__ballot(vmax - y < THRF) >> shamt) & 0xFFFFull);
    int idx;
    if (__builtin_popcount(bal) > 1) {
      float gp = gumbel_precise(PK0, PK1, (unsigned)(gb * 80 + h * 10 + lane));
      float yp = on ? (logit + gp) : -3.0e38f;
      float vp = redmax16(yp);
      idx = __builtin_ctz((unsigned)((__ballot(yp == vp) >> shamt) & 0xFFFFull));
    } else {
      idx = __builtin_ctz(bal);
    }
    float s = redsum16(on ? __expf(logit) : 0.0f);
    float mlidx = redmax16((lane == idx) ? logit : -3.0e38f);
    float lp = mlidx - __logf(s);
    int ah = (int)((avm >> (8 + h)) & 1u);
    if (ah) lpsum += lp;
    if (lane == 8 + h) my_act = ah ? (float)idx : -1.0f;
  }

  out[(size_t)gb * 16 + lane] = my_act;
  if (lane == 0) out[(size_t)B_TOTAL * 16 + gb] = lpsum;
  out[(size_t)B_TOTAL * 17 + (size_t)gb * 16 + lane] = (float)av;
}

extern "C" void kernel_launch(void* const* d_in, const int* in_sizes, int n_in,
                              void* d_out, int out_size, void* d_ws, size_t ws_size,
                              hipStream_t stream) {
  const float* x    = (const float*)d_in[0];
  const int*   av   = (const int*)  d_in[1];
  const float* Wsc  = (const float*)d_in[2];
  const float* bsc  = (const float*)d_in[3];
  const float* Wpow = (const float*)d_in[4];
  const float* bpow = (const float*)d_in[5];
  float* outp = (float*)d_out;

  float* bp = (float*)d_ws;                             // 256 floats
  short* Wb = (short*)((char*)d_ws + 1024);             // 3*53248 shorts
  const size_t lgoff = 1024 + (size_t)3 * WPLANE * sizeof(short);   // 320512
  float* lgT = (float*)((char*)d_ws + lgoff);
  const size_t need = lgoff + (size_t)NCOL * B_TOTAL * sizeof(float);

  repack_kernel<<<209, 256, 0, stream>>>(Wsc, bsc, Wpow, bpow, Wb, bp);
  if (ws_size >= need) {
    gemm_kernel<<<B_TOTAL / ROWS, 512, 0, stream>>>(x, Wb, bp, lgT);
    sample_kernel<<<B_TOTAL / 16, 256, 0, stream>>>(lgT, av, outp);
  } else {
    act_kernel<<<B_TOTAL / ROWS, 512, 0, stream>>>(x, av, Wb, bp, outp);
  }
}